// Round 1
// baseline (1848.648 us; speedup 1.0000x reference)
//
#include <hip/hip_runtime.h>

// Problem constants (fixed by the reference: N=65536, K=4096, D=128).
constexpr int N_PTS   = 65536;
constexpr int K_CENT  = 4096;
constexpr int D_DIM   = 128;
constexpr int KCHUNKS = 4;                 // split K for occupancy (4 waves/SIMD-ish)
constexpr int KC      = K_CENT / KCHUNKS;  // 1024 centroids per chunk

// ---------------------------------------------------------------------------
// Kernel 1: c2[k] = sum_d coords[k][d]^2
// ---------------------------------------------------------------------------
__global__ __launch_bounds__(256) void c2_kernel(const float* __restrict__ coords,
                                                 float* __restrict__ c2) {
    int k = blockIdx.x * 256 + threadIdx.x;
    if (k >= K_CENT) return;
    const float* c = coords + (size_t)k * D_DIM;
    float s = 0.f;
#pragma unroll
    for (int d = 0; d < D_DIM; ++d) s = fmaf(c[d], c[d], s);
    c2[k] = s;
}

// ---------------------------------------------------------------------------
// Kernel 2: per-point partial argmin over one K-chunk.
// One point per thread; latent row held in 128 VGPRs; coords accessed at
// wave-uniform addresses so the compiler emits s_load -> pure v_fmac inner loop.
// score = c2[k] - 2*dot  (x^2 is constant per point; sqrt is monotone).
// ---------------------------------------------------------------------------
__global__ __launch_bounds__(256, 3) void argmin_partial(
        const float* __restrict__ latent,
        const float* __restrict__ coords,
        const float* __restrict__ c2,
        float* __restrict__ part_score,
        int*   __restrict__ part_idx) {
    const int chunk = blockIdx.y;
    const int n = blockIdx.x * 256 + threadIdx.x;

    // Load this point's latent row into registers (32 x float4).
    const float* lp = latent + (size_t)n * D_DIM;
    float lat[D_DIM];
#pragma unroll
    for (int d = 0; d < D_DIM; d += 4) {
        float4 v = *(const float4*)(lp + d);
        lat[d] = v.x; lat[d + 1] = v.y; lat[d + 2] = v.z; lat[d + 3] = v.w;
    }

    const int k0 = chunk * KC;
    float best = 3.4e38f;
    int   besti = k0;

    for (int k = k0; k < k0 + KC; k += 2) {
        const float* c0 = coords + (size_t)k * D_DIM;  // wave-uniform address
        float a0 = 0.f, b0 = 0.f, a1 = 0.f, b1 = 0.f;  // 4 indep FMA chains
#pragma unroll
        for (int d = 0; d < D_DIM; d += 2) {
            a0 = fmaf(c0[d],             lat[d],     a0);
            b0 = fmaf(c0[d + 1],         lat[d + 1], b0);
            a1 = fmaf(c0[D_DIM + d],     lat[d],     a1);
            b1 = fmaf(c0[D_DIM + d + 1], lat[d + 1], b1);
        }
        float s0 = fmaf(-2.f, a0 + b0, c2[k]);
        float s1 = fmaf(-2.f, a1 + b1, c2[k + 1]);
        // Ascending k with strict < keeps the FIRST minimum (jnp.argmin tie rule).
        if (s0 < best) { best = s0; besti = k; }
        if (s1 < best) { best = s1; besti = k + 1; }
    }

    part_score[(size_t)chunk * N_PTS + n] = best;
    part_idx  [(size_t)chunk * N_PTS + n] = besti;
}

// ---------------------------------------------------------------------------
// Kernel 3: combine the KCHUNKS candidates per point.
// Chunk-ascending scan with strict < preserves lowest-index-on-tie.
// ---------------------------------------------------------------------------
__global__ __launch_bounds__(256) void argmin_combine(
        const float* __restrict__ part_score,
        const int*   __restrict__ part_idx,
        int*         __restrict__ out) {
    const int n = blockIdx.x * 256 + threadIdx.x;
    float best  = part_score[n];
    int   besti = part_idx[n];
#pragma unroll
    for (int c = 1; c < KCHUNKS; ++c) {
        float s = part_score[(size_t)c * N_PTS + n];
        int   i = part_idx  [(size_t)c * N_PTS + n];
        if (s < best) { best = s; besti = i; }
    }
    out[n] = besti;
}

// ---------------------------------------------------------------------------
extern "C" void kernel_launch(void* const* d_in, const int* in_sizes, int n_in,
                              void* d_out, int out_size, void* d_ws, size_t ws_size,
                              hipStream_t stream) {
    const float* latent = (const float*)d_in[0];  // [N, D] fp32
    const float* coords = (const float*)d_in[1];  // [K, D] fp32
    int* out = (int*)d_out;                       // [N] int32 indices

    // Workspace layout: scores[KCHUNKS][N] | idxs[KCHUNKS][N] | c2[K]
    float* part_score = (float*)d_ws;
    int*   part_idx   = (int*)(part_score + (size_t)KCHUNKS * N_PTS);
    float* c2         = (float*)(part_idx + (size_t)KCHUNKS * N_PTS);

    c2_kernel<<<dim3((K_CENT + 255) / 256), dim3(256), 0, stream>>>(coords, c2);

    dim3 grid(N_PTS / 256, KCHUNKS);
    argmin_partial<<<grid, dim3(256), 0, stream>>>(latent, coords, c2,
                                                   part_score, part_idx);

    argmin_combine<<<dim3(N_PTS / 256), dim3(256), 0, stream>>>(part_score,
                                                                part_idx, out);
}